// Round 6
// baseline (374.600 us; speedup 1.0000x reference)
//
#include <hip/hip_runtime.h>
#include <math.h>

#define BB 4
#define SS 1024
#define DD 1024
#define HH 16
#define DHH 64

typedef _Float16 half8 __attribute__((ext_vector_type(8)));
typedef _Float16 half4v __attribute__((ext_vector_type(4)));
typedef float v4f __attribute__((ext_vector_type(4)));
typedef unsigned int u32;
typedef unsigned short u16;

// async global->LDS, 16B/lane. LDS dest is wave-uniform base + lane*16.
__device__ __forceinline__ void gload_lds16(const void* g, void* l) {
    __builtin_amdgcn_global_load_lds(
        (const __attribute__((address_space(1))) u32*)(const u32*)g,
        (__attribute__((address_space(3))) u32*)(u32*)l, 16, 0, 0);
}

// ---------------------------------------------------------------------------
// convert: W_q, W_k(*0.125), W_v, W_o, pe(*8)  fp32 -> f16  (R2-verified)
// ---------------------------------------------------------------------------
__global__ __launch_bounds__(256) void convert_kernel(
    const float* __restrict__ wq, const float* __restrict__ wk,
    const float* __restrict__ wv, const float* __restrict__ wo,
    const float* __restrict__ pe, _Float16* __restrict__ dst)
{
    const int i4 = blockIdx.x * 256 + threadIdx.x;
    const int region = i4 >> 18;
    const int local4 = i4 & 262143;
    const float* srcs[5] = {wq, wk, wv, wo, pe};
    const float scales[5] = {1.0f, 0.125f, 1.0f, 1.0f, 8.0f};
    const float sc = scales[region];
    float4 v = *(const float4*)(srcs[region] + (size_t)local4 * 4);
    half4v h = {(_Float16)(v.x * sc), (_Float16)(v.y * sc),
                (_Float16)(v.z * sc), (_Float16)(v.w * sc)};
    *(half4v*)(dst + ((size_t)region << 20) + (size_t)local4 * 4) = h;
}

// ---------------------------------------------------------------------------
// convert query/key/value (fp32 [B,S,D]) -> f16, straight copy
// ---------------------------------------------------------------------------
__global__ __launch_bounds__(256) void convert_qkv(
    const float* __restrict__ q, const float* __restrict__ k,
    const float* __restrict__ v, _Float16* __restrict__ dst)
{
    const int i4 = blockIdx.x * 256 + threadIdx.x;     // 0 .. 3M
    const int region = i4 >> 20;                       // 1M float4 per input
    const int local4 = i4 & 1048575;
    const float* srcs[3] = {q, k, v};
    float4 x = *(const float4*)(srcs[region] + (size_t)local4 * 4);
    half4v h = {(_Float16)x.x, (_Float16)x.y, (_Float16)x.z, (_Float16)x.w};
    *(half4v*)(dst + ((size_t)region << 22) + (size_t)local4 * 4) = h;
}

// ---------------------------------------------------------------------------
// f16 MFMA GEMM (R2-VERIFIED template): C = A (MxK,f16) * W^T, fp32 acc.
// 128x128 tile, BK=32, 4 waves (2x2 of 64x64), dual global_load_lds DMA.
// C_MODE=0: fp32 row-major.  C_MODE=1: f16 [B,H,S,DH] relayout.
// ---------------------------------------------------------------------------
template<int C_MODE>
__global__ __launch_bounds__(256) void gemm_f16(
    const _Float16* __restrict__ A, const _Float16* __restrict__ W,
    void* __restrict__ Cp, int M, int K)
{
    __shared__ _Float16 As[128 * 32];
    __shared__ _Float16 Bs[128 * 32];

    const int tid = threadIdx.x;
    const int n0 = blockIdx.x * 128;
    const int m0 = blockIdx.y * 128;
    const int w = tid >> 6, lane = tid & 63;
    const int lm = lane & 15, quad = lane >> 4;
    const int wr = w >> 1, wc = w & 1;

    v4f zero4 = {0.f, 0.f, 0.f, 0.f};
    v4f acc[4][4];
#pragma unroll
    for (int mi = 0; mi < 4; mi++)
#pragma unroll
        for (int ni = 0; ni < 4; ni++) acc[mi][ni] = zero4;

    for (int k0 = 0; k0 < K; k0 += 32) {
        __syncthreads();
#pragma unroll
        for (int u = 0; u < 2; u++) {
            int c = tid + 256 * u;
            int row = c >> 2, k8 = c & 3;
            gload_lds16(A + (size_t)(m0 + row) * K + k0 + k8 * 8, As + c * 8);
        }
#pragma unroll
        for (int u = 0; u < 2; u++) {
            int c = tid + 256 * u;
            int row = c >> 2, k8 = c & 3;
            gload_lds16(W + (size_t)(n0 + row) * K + k0 + k8 * 8, Bs + c * 8);
        }
        __syncthreads();

        half8 af[4], bf[4];
#pragma unroll
        for (int mi = 0; mi < 4; mi++)
            af[mi] = *(const half8*)(As + (wr * 64 + mi * 16 + lm) * 32 + quad * 8);
#pragma unroll
        for (int ni = 0; ni < 4; ni++)
            bf[ni] = *(const half8*)(Bs + (wc * 64 + ni * 16 + lm) * 32 + quad * 8);
#pragma unroll
        for (int mi = 0; mi < 4; mi++)
#pragma unroll
            for (int ni = 0; ni < 4; ni++)
                acc[mi][ni] = __builtin_amdgcn_mfma_f32_16x16x32_f16(
                    af[mi], bf[ni], acc[mi][ni], 0, 0, 0);
    }

    if (C_MODE == 1) {
        _Float16* C = (_Float16*)Cp;
        const int h = (n0 + wc * 64) >> 6;      // wave's 64 cols = one head
        const int d = lm;
#pragma unroll
        for (int mi = 0; mi < 4; mi++)
#pragma unroll
            for (int r = 0; r < 4; r++) {
                int m = m0 + wr * 64 + mi * 16 + quad * 4 + r;
                int b = m >> 10, s = m & 1023;
                size_t base = (((size_t)(b * HH + h) << 10) + s) * DHH;
#pragma unroll
                for (int ni = 0; ni < 4; ni++)
                    C[base + ni * 16 + d] = (_Float16)acc[mi][ni][r];
            }
    } else {
        float* C = (float*)Cp;
#pragma unroll
        for (int mi = 0; mi < 4; mi++)
#pragma unroll
            for (int r = 0; r < 4; r++) {
                size_t base = (size_t)(m0 + wr * 64 + mi * 16 + quad * 4 + r) * DD
                            + n0 + wc * 64 + lm;
#pragma unroll
                for (int ni = 0; ni < 4; ni++)
                    C[base + ni * 16] = acc[mi][ni][r];
            }
    }
}

// ---------------------------------------------------------------------------
// MFMA flash attention — R2/R5 structure VERBATIM except:
//  * Qs/Ks/PEb row stride 64 -> 72 f16 (pad; frag reads 16-way -> 2-way)
//  * Q/K/PE staged with explicit vector loads + padded LDS writes (no DMA)
//  * loop-invariant Q fragments hoisted out of the j-loop
// ---------------------------------------------------------------------------
__global__ __launch_bounds__(256) void attn_mfma(
    const _Float16* __restrict__ Qg, const _Float16* __restrict__ Kg,
    const _Float16* __restrict__ Vg, const int* __restrict__ mask,
    const _Float16* __restrict__ peg, _Float16* __restrict__ Og)
{
    __shared__ _Float16 Qs[64 * 72];        // 9 KB  padded
    __shared__ _Float16 Ks[64 * 72];        // 9 KB  padded
    __shared__ _Float16 Vt[64 * 72];        // 9 KB  [d][j], padded
    __shared__ _Float16 PEb[128 * 72];      // 18 KB [o][d], padded
    __shared__ float    Rb[4][16 * 130];    // 33.3 KB per-wave scratch (P overlays)

    const int tid = threadIdx.x;
    const int w = tid >> 6, lane = tid & 63;
    const int lm = lane & 15, quad = lane >> 4;
    const int it = blockIdx.x, i0 = it * 64;
    const int bh = blockIdx.y, b = bh >> 4, h = bh & 15;

    const _Float16* Qb = Qg + (size_t)bh * SS * DHH;
    const _Float16* Kb = Kg + (size_t)bh * SS * DHH;
    const _Float16* Vb = Vg + (size_t)bh * SS * DHH;
    const _Float16* peh = peg + (size_t)h * SS * DHH;

    // stage Q once (manual, padded)
#pragma unroll
    for (int u = 0; u < 2; u++) {
        int c = tid + 256 * u;
        int row = c >> 3, k8 = c & 7;
        half8 v = *(const half8*)(Qb + (size_t)(i0 + row) * DHH + k8 * 8);
        *(half8*)(Qs + row * 72 + k8 * 8) = v;
    }

    float mi_f[4];
#pragma unroll
    for (int r = 0; r < 4; r++)
        mi_f[r] = (float)mask[b * SS + i0 + w * 16 + quad * 4 + r];
    __syncthreads();

    // hoisted loop-invariant Q fragments
    half8 qf[2];
#pragma unroll
    for (int kc = 0; kc < 2; kc++)
        qf[kc] = *(const half8*)(Qs + (w * 16 + lm) * 72 + kc * 32 + quad * 8);

    v4f zero4 = {0.f, 0.f, 0.f, 0.f};
    float m_run[4], l_run[4];
    v4f oacc[4];
#pragma unroll
    for (int r = 0; r < 4; r++) { m_run[r] = -1e30f; l_run[r] = 0.f; }
#pragma unroll
    for (int nb = 0; nb < 4; nb++) oacc[nb] = zero4;

    for (int jt = 0; jt < SS / 64; jt++) {
        const int j0 = jt * 64;
        const bool do_pe = (jt <= it);
        __syncthreads();                                   // (a) prev-iter LDS reads done

        // stage K (manual, padded)
#pragma unroll
        for (int u = 0; u < 2; u++) {
            int c = tid + 256 * u;
            int row = c >> 3, k8 = c & 7;
            half8 v = *(const half8*)(Kb + (size_t)(j0 + row) * DHH + k8 * 8);
            *(half8*)(Ks + row * 72 + k8 * 8) = v;
        }
        // stage V transposed (verbatim)
#pragma unroll
        for (int u = 0; u < 2; u++) {
            int c = tid + 256 * u;
            int row = c >> 3, k8 = c & 7;
            half8 v = *(const half8*)(Vb + (size_t)(j0 + row) * DHH + k8 * 8);
#pragma unroll
            for (int e = 0; e < 8; e++) Vt[(k8 * 8 + e) * 72 + row] = v[e];
        }
        // stage PE band (128 rows x 64; manual, padded)
        if (do_pe) {
            const int g0 = SS - 1 + j0 - i0 - 63;          // in [0, 960]
#pragma unroll
            for (int u = 0; u < 4; u++) {
                int c = tid + 256 * u;
                int o = c >> 3, k8 = c & 7;
                int g = g0 + o;
                half8 v = {0, 0, 0, 0, 0, 0, 0, 0};
                if (g < SS) v = *(const half8*)(peh + (size_t)g * DHH + k8 * 8);
                *(half8*)(PEb + o * 72 + k8 * 8) = v;
            }
        }
        float mj_f[4];
#pragma unroll
        for (int nb = 0; nb < 4; nb++)
            mj_f[nb] = (float)mask[b * SS + j0 + nb * 16 + lm];
        __syncthreads();                                   // (b) staging visible

        // ---- QK^T
        v4f sacc[4];
#pragma unroll
        for (int nb = 0; nb < 4; nb++) sacc[nb] = zero4;
#pragma unroll
        for (int nb = 0; nb < 4; nb++)
#pragma unroll
            for (int kc = 0; kc < 2; kc++) {
                half8 kf = *(const half8*)(Ks + (nb * 16 + lm) * 72 + kc * 32 + quad * 8);
                sacc[nb] = __builtin_amdgcn_mfma_f32_16x16x32_f16(qf[kc], kf, sacc[nb], 0, 0, 0);
            }

        // ---- relative position band
        if (do_pe) {
            v4f racc[8];
#pragma unroll
            for (int cb = 0; cb < 8; cb++) racc[cb] = zero4;
#pragma unroll
            for (int cb = 0; cb < 8; cb++)
#pragma unroll
                for (int kc = 0; kc < 2; kc++) {
                    half8 pf = *(const half8*)(PEb + (cb * 16 + lm) * 72 + kc * 32 + quad * 8);
                    racc[cb] = __builtin_amdgcn_mfma_f32_16x16x32_f16(qf[kc], pf, racc[cb], 0, 0, 0);
                }
            float* Rw = &Rb[w][0];
#pragma unroll
            for (int cb = 0; cb < 8; cb++)
#pragma unroll
                for (int r = 0; r < 4; r++)
                    Rw[(quad * 4 + r) * 130 + cb * 16 + lm] = racc[cb][r];
            __syncthreads();                               // (c) Rb visible
            // gather diagonal: c = jc - i_rel + 63
#pragma unroll
            for (int nb = 0; nb < 4; nb++)
#pragma unroll
                for (int r = 0; r < 4; r++) {
                    int c = nb * 16 + lm - (w * 16 + quad * 4 + r) + 63;
                    sacc[nb][r] += Rw[(quad * 4 + r) * 130 + c];
                }
            __syncthreads();                               // (d) gather done before P overlay
        }

        // ---- mask + online softmax (verbatim)
        float p[4][4];
        float alpha[4];
#pragma unroll
        for (int i = 0; i < 4; i++) {
            float mi = mi_f[i];
            float rmax = -1e30f;
#pragma unroll
            for (int j = 0; j < 4; j++) {
                float s = sacc[j][i];
                if (mi * mj_f[j] == 0.f) s = -1e9f;
                sacc[j][i] = s;
                rmax = fmaxf(rmax, s);
            }
#pragma unroll
            for (int off = 1; off < 16; off <<= 1)
                rmax = fmaxf(rmax, __shfl_xor(rmax, off));
            float mnew = fmaxf(m_run[i], rmax);
            alpha[i] = __expf(m_run[i] - mnew);
            m_run[i] = mnew;
            float rsum = 0.f;
#pragma unroll
            for (int j = 0; j < 4; j++) {
                p[j][i] = __expf(sacc[j][i] - mnew);
                rsum += p[j][i];
            }
#pragma unroll
            for (int off = 1; off < 16; off <<= 1)
                rsum += __shfl_xor(rsum, off);
            l_run[i] = l_run[i] * alpha[i] + rsum;
        }

        // write P (f16) into per-wave overlay; rescale O
        _Float16* Pw = (_Float16*)&Rb[w][0];
#pragma unroll
        for (int nb = 0; nb < 4; nb++)
#pragma unroll
            for (int r = 0; r < 4; r++)
                Pw[(quad * 4 + r) * 72 + nb * 16 + lm] = (_Float16)p[nb][r];
#pragma unroll
        for (int nb = 0; nb < 4; nb++)
#pragma unroll
            for (int r = 0; r < 4; r++) oacc[nb][r] *= alpha[r];
        __syncthreads();                                   // (e) P visible

        // ---- PV
#pragma unroll
        for (int kc = 0; kc < 2; kc++) {
            half8 pfrag = *(const half8*)(Pw + lm * 72 + kc * 32 + quad * 8);
#pragma unroll
            for (int nb = 0; nb < 4; nb++) {
                half8 vfrag = *(const half8*)(Vt + (nb * 16 + lm) * 72 + kc * 32 + quad * 8);
                oacc[nb] = __builtin_amdgcn_mfma_f32_16x16x32_f16(pfrag, vfrag, oacc[nb], 0, 0, 0);
            }
        }
    }

    // epilogue: normalize, write f16 [B,S,D]
#pragma unroll
    for (int r = 0; r < 4; r++) {
        float inv = 1.f / l_run[r];
        int s = i0 + w * 16 + quad * 4 + r;
#pragma unroll
        for (int nb = 0; nb < 4; nb++)
            Og[((size_t)b * SS + s) * DD + h * DHH + nb * 16 + lm] =
                (_Float16)(oacc[nb][r] * inv);
    }
}

extern "C" void kernel_launch(void* const* d_in, const int* in_sizes, int n_in,
                              void* d_out, int out_size, void* d_ws, size_t ws_size,
                              hipStream_t stream)
{
    const float* query = (const float*)d_in[0];
    const float* key   = (const float*)d_in[1];
    const float* value = (const float*)d_in[2];
    const int*   mask  = (const int*)d_in[3];
    const float* pe    = (const float*)d_in[4];
    const float* Wq    = (const float*)d_in[5];
    const float* Wk    = (const float*)d_in[6];
    const float* Wv    = (const float*)d_in[7];
    const float* Wo    = (const float*)d_in[8];
    float* out = (float*)d_out;

    _Float16* ws16 = (_Float16*)d_ws;
    const size_t MEG = 1048576;
    _Float16* wqf = ws16;
    _Float16* wkf = ws16 + 1 * MEG;
    _Float16* wvf = ws16 + 2 * MEG;
    _Float16* wof = ws16 + 3 * MEG;
    _Float16* pef = ws16 + 4 * MEG;
    _Float16* qp  = ws16 + 5 * MEG;     // [B,H,S,DH]
    _Float16* kp  = ws16 + 9 * MEG;     // [B,H,S,DH]
    _Float16* vp  = ws16 + 13 * MEG;    // [B,H,S,DH]
    _Float16* ao  = ws16 + 17 * MEG;    // [B,S,D]  (overlays qin; qin dead by then)
    _Float16* qin = ws16 + 17 * MEG;    // f16 [B,S,D] converted inputs
    _Float16* kin = ws16 + 21 * MEG;
    _Float16* vin = ws16 + 25 * MEG;

    convert_kernel<<<5120, 256, 0, stream>>>(Wq, Wk, Wv, Wo, pe, ws16);
    convert_qkv<<<12288, 256, 0, stream>>>(query, key, value, qin);

    dim3 ggrid(DD / 128, (BB * SS) / 128);   // (8, 32)
    gemm_f16<1><<<ggrid, 256, 0, stream>>>(qin, wqf, qp, BB * SS, DD);
    gemm_f16<1><<<ggrid, 256, 0, stream>>>(kin, wkf, kp, BB * SS, DD);
    gemm_f16<1><<<ggrid, 256, 0, stream>>>(vin, wvf, vp, BB * SS, DD);

    attn_mfma<<<dim3(SS / 64, BB * HH), 256, 0, stream>>>(qp, kp, vp, mask, pef, ao);

    gemm_f16<0><<<ggrid, 256, 0, stream>>>(ao, wof, out, BB * SS, DD);
}

// Round 9
// 336.634 us; speedup vs baseline: 1.1128x; 1.1128x over previous
//
#include <hip/hip_runtime.h>
#include <math.h>

#define BB 4
#define SS 1024
#define DD 1024
#define HH 16
#define DHH 64

typedef _Float16 half8 __attribute__((ext_vector_type(8)));
typedef _Float16 half4v __attribute__((ext_vector_type(4)));
typedef float v4f __attribute__((ext_vector_type(4)));
typedef unsigned int u32;
typedef unsigned short u16;

// async global->LDS, 16B/lane. LDS dest is wave-uniform base + lane*16.
__device__ __forceinline__ void gload_lds16(const void* g, void* l) {
    __builtin_amdgcn_global_load_lds(
        (const __attribute__((address_space(1))) u32*)(const u32*)g,
        (__attribute__((address_space(3))) u32*)(u32*)l, 16, 0, 0);
}

// ---------------------------------------------------------------------------
// convert: W_q, W_k(*0.125), W_v, W_o, pe(*8)  fp32 -> f16  (verified)
// ---------------------------------------------------------------------------
__global__ __launch_bounds__(256) void convert_kernel(
    const float* __restrict__ wq, const float* __restrict__ wk,
    const float* __restrict__ wv, const float* __restrict__ wo,
    const float* __restrict__ pe, _Float16* __restrict__ dst)
{
    const int i4 = blockIdx.x * 256 + threadIdx.x;
    const int region = i4 >> 18;
    const int local4 = i4 & 262143;
    const float* srcs[5] = {wq, wk, wv, wo, pe};
    const float scales[5] = {1.0f, 0.125f, 1.0f, 1.0f, 8.0f};
    const float sc = scales[region];
    float4 v = *(const float4*)(srcs[region] + (size_t)local4 * 4);
    half4v h = {(_Float16)(v.x * sc), (_Float16)(v.y * sc),
                (_Float16)(v.z * sc), (_Float16)(v.w * sc)};
    *(half4v*)(dst + ((size_t)region << 20) + (size_t)local4 * 4) = h;
}

// ---------------------------------------------------------------------------
// Fused Q/K/V projection GEMMs (z = 0,1,2)  (R5-VERIFIED, twice)
// ---------------------------------------------------------------------------
__global__ __launch_bounds__(256) void gemm_proj(
    const float* __restrict__ Aq, const float* __restrict__ Ak,
    const float* __restrict__ Av,
    const _Float16* __restrict__ Wqf, const _Float16* __restrict__ Wkf,
    const _Float16* __restrict__ Wvf,
    _Float16* __restrict__ Cq, _Float16* __restrict__ Ck,
    _Float16* __restrict__ Cv)
{
    __shared__ _Float16 As[128 * 32];
    __shared__ _Float16 Bs[64 * 32];

    const int z = blockIdx.z;
    const float* A = z == 0 ? Aq : z == 1 ? Ak : Av;
    const _Float16* W = z == 0 ? Wqf : z == 1 ? Wkf : Wvf;
    _Float16* C = z == 0 ? Cq : z == 1 ? Ck : Cv;

    const int tid = threadIdx.x;
    const int w = tid >> 6, lane = tid & 63, lm = lane & 15, quad = lane >> 4;
    const int n0 = blockIdx.x * 64, m0 = blockIdx.y * 128;

    const int brow = tid >> 2, blc = (tid & 3) ^ (brow & 3);

    v4f zero4 = {0.f, 0.f, 0.f, 0.f};
    v4f acc[2][4];
#pragma unroll
    for (int mi = 0; mi < 2; mi++)
#pragma unroll
        for (int ni = 0; ni < 4; ni++) acc[mi][ni] = zero4;

    for (int k0 = 0; k0 < DD; k0 += 32) {
        __syncthreads();
        gload_lds16(W + (size_t)(n0 + brow) * DD + k0 + blc * 8, Bs + tid * 8);
#pragma unroll
        for (int u = 0; u < 4; u++) {
            int c4 = tid + 256 * u;
            int row = c4 >> 3, k4 = c4 & 7;
            float4 v = *(const float4*)(A + (size_t)(m0 + row) * DD + k0 + k4 * 4);
            half4v hv = {(_Float16)v.x, (_Float16)v.y, (_Float16)v.z, (_Float16)v.w};
            int c16 = k4 >> 1, hlf = k4 & 1;
            *(half4v*)(As + row * 32 + (((c16 ^ (row & 3)) << 3) + (hlf << 2))) = hv;
        }
        __syncthreads();

        half8 af[2], bf[4];
#pragma unroll
        for (int mi = 0; mi < 2; mi++) {
            int row = w * 32 + mi * 16 + lm;
            af[mi] = *(const half8*)(As + row * 32 + ((quad ^ (row & 3)) << 3));
        }
#pragma unroll
        for (int ni = 0; ni < 4; ni++) {
            int row = ni * 16 + lm;
            bf[ni] = *(const half8*)(Bs + row * 32 + ((quad ^ (row & 3)) << 3));
        }
#pragma unroll
        for (int mi = 0; mi < 2; mi++)
#pragma unroll
            for (int ni = 0; ni < 4; ni++)
                acc[mi][ni] = __builtin_amdgcn_mfma_f32_16x16x32_f16(
                    af[mi], bf[ni], acc[mi][ni], 0, 0, 0);
    }

    const int h = n0 >> 6;
#pragma unroll
    for (int mi = 0; mi < 2; mi++)
#pragma unroll
        for (int r = 0; r < 4; r++) {
            int m = m0 + w * 32 + mi * 16 + quad * 4 + r;
            int b = m >> 10, s = m & 1023;
            size_t base = ((size_t)(b * HH + h) * SS + s) * DHH;
#pragma unroll
            for (int ni = 0; ni < 4; ni++)
                C[base + ni * 16 + lm] = (_Float16)acc[mi][ni][r];
        }
}

// ---------------------------------------------------------------------------
// Output GEMM: C(fp32 4096x1024) = A(f16) * W^T.  (R5-VERIFIED, twice)
// ---------------------------------------------------------------------------
__global__ __launch_bounds__(256) void gemm_out(
    const _Float16* __restrict__ A, const _Float16* __restrict__ W,
    float* __restrict__ C)
{
    __shared__ _Float16 As[128 * 32];
    __shared__ _Float16 Bs[64 * 32];

    const int tid = threadIdx.x;
    const int w = tid >> 6, lane = tid & 63, lm = lane & 15, quad = lane >> 4;
    const int n0 = blockIdx.x * 64, m0 = blockIdx.y * 128;
    const int brow = tid >> 2, blc = (tid & 3) ^ (brow & 3);

    v4f zero4 = {0.f, 0.f, 0.f, 0.f};
    v4f acc[2][4];
#pragma unroll
    for (int mi = 0; mi < 2; mi++)
#pragma unroll
        for (int ni = 0; ni < 4; ni++) acc[mi][ni] = zero4;

    for (int k0 = 0; k0 < DD; k0 += 32) {
        __syncthreads();
        gload_lds16(W + (size_t)(n0 + brow) * DD + k0 + blc * 8, Bs + tid * 8);
#pragma unroll
        for (int u = 0; u < 2; u++) {
            int p = tid + 256 * u;
            int row = p >> 2, lc = (p & 3) ^ (row & 3);
            gload_lds16(A + (size_t)(m0 + row) * DD + k0 + lc * 8, As + p * 8);
        }
        __syncthreads();

        half8 af[2], bf[4];
#pragma unroll
        for (int mi = 0; mi < 2; mi++) {
            int row = w * 32 + mi * 16 + lm;
            af[mi] = *(const half8*)(As + row * 32 + ((quad ^ (row & 3)) << 3));
        }
#pragma unroll
        for (int ni = 0; ni < 4; ni++) {
            int row = ni * 16 + lm;
            bf[ni] = *(const half8*)(Bs + row * 32 + ((quad ^ (row & 3)) << 3));
        }
#pragma unroll
        for (int mi = 0; mi < 2; mi++)
#pragma unroll
            for (int ni = 0; ni < 4; ni++)
                acc[mi][ni] = __builtin_amdgcn_mfma_f32_16x16x32_f16(
                    af[mi], bf[ni], acc[mi][ni], 0, 0, 0);
    }

#pragma unroll
    for (int mi = 0; mi < 2; mi++)
#pragma unroll
        for (int r = 0; r < 4; r++) {
            size_t base = (size_t)(m0 + w * 32 + mi * 16 + quad * 4 + r) * DD
                        + n0 + lm;
#pragma unroll
            for (int ni = 0; ni < 4; ni++)
                C[base + ni * 16] = acc[mi][ni][r];
        }
}

// ---------------------------------------------------------------------------
// MFMA flash attention — R6-PASSING kernel with EXACTLY ONE change (bisect
// variable A): the 8-tile band + LDS round-trip gather is replaced by a
// 5-tile band + __shfl diagonal gather.  Everything else (dedicated P
// buffer, scalar V staging, barriers a/b/e, padded stride-72 LDS) is R6
// verbatim.  Wave w needs PE tiles cb in [3-w, 7-w] only; union over waves
// is all 8 tiles, so block-level staging is unchanged.
// Gather: element (nb,r) at lane (quad,lm), qr=quad*4+r:
//   t_target = nb*16+lm - (w*16+qr) + 63  (w cancels against tile base)
//   provider lane lm_s = (lm-qr-1)&15 in same quad; provider exposes
//   racc[nb] if ((lm_s... own lm+qr+1)&15)<=qr else racc[nb+1].
// j>i contributes 0 via zero-filled PE rows g>=S (verified: zero for t>=64
// on the diagonal tile, never reached on earlier tiles).
// ---------------------------------------------------------------------------
__global__ __launch_bounds__(256) void attn_mfma(
    const _Float16* __restrict__ Qg, const _Float16* __restrict__ Kg,
    const _Float16* __restrict__ Vg, const int* __restrict__ mask,
    const _Float16* __restrict__ peg, _Float16* __restrict__ Og)
{
    __shared__ _Float16 Qs[64 * 72];        // 9 KB  padded
    __shared__ _Float16 Ks[64 * 72];        // 9 KB  padded
    __shared__ _Float16 Vt[64 * 72];        // 9 KB  [d][j], padded
    __shared__ _Float16 PEb[128 * 72];      // 18 KB [o][d], padded
    __shared__ _Float16 Pb[4][16 * 72];     // 9 KB  per-wave P (dedicated)

    const int tid = threadIdx.x;
    const int w = tid >> 6, lane = tid & 63;
    const int lm = lane & 15, quad = lane >> 4;
    const int it = blockIdx.x, i0 = it * 64;
    const int bh = blockIdx.y, b = bh >> 4, h = bh & 15;

    const _Float16* Qb = Qg + (size_t)bh * SS * DHH;
    const _Float16* Kb = Kg + (size_t)bh * SS * DHH;
    const _Float16* Vb = Vg + (size_t)bh * SS * DHH;
    const _Float16* peh = peg + (size_t)h * SS * DHH;

    // stage Q once (manual, padded)
#pragma unroll
    for (int u = 0; u < 2; u++) {
        int c = tid + 256 * u;
        int row = c >> 3, k8 = c & 7;
        half8 v = *(const half8*)(Qb + (size_t)(i0 + row) * DHH + k8 * 8);
        *(half8*)(Qs + row * 72 + k8 * 8) = v;
    }

    float mi_f[4];
#pragma unroll
    for (int r = 0; r < 4; r++)
        mi_f[r] = (float)mask[b * SS + i0 + w * 16 + quad * 4 + r];
    __syncthreads();

    // hoisted loop-invariant Q fragments
    half8 qf[2];
#pragma unroll
    for (int kc = 0; kc < 2; kc++)
        qf[kc] = *(const half8*)(Qs + (w * 16 + lm) * 72 + kc * 32 + quad * 8);

    v4f zero4 = {0.f, 0.f, 0.f, 0.f};
    float m_run[4], l_run[4];
    v4f oacc[4];
#pragma unroll
    for (int r = 0; r < 4; r++) { m_run[r] = -1e30f; l_run[r] = 0.f; }
#pragma unroll
    for (int nb = 0; nb < 4; nb++) oacc[nb] = zero4;

    for (int jt = 0; jt < SS / 64; jt++) {
        const int j0 = jt * 64;
        const bool do_pe = (jt <= it);
        __syncthreads();                                   // (a) prev-iter reads done

        // stage K (manual, padded)  [R6 verbatim]
#pragma unroll
        for (int u = 0; u < 2; u++) {
            int c = tid + 256 * u;
            int row = c >> 3, k8 = c & 7;
            half8 v = *(const half8*)(Kb + (size_t)(j0 + row) * DHH + k8 * 8);
            *(half8*)(Ks + row * 72 + k8 * 8) = v;
        }
        // stage V transposed  [R6 verbatim]
#pragma unroll
        for (int u = 0; u < 2; u++) {
            int c = tid + 256 * u;
            int row = c >> 3, k8 = c & 7;
            half8 v = *(const half8*)(Vb + (size_t)(j0 + row) * DHH + k8 * 8);
#pragma unroll
            for (int e = 0; e < 8; e++) Vt[(k8 * 8 + e) * 72 + row] = v[e];
        }
        // stage PE band (128 rows x 64; zero-fill OOB)  [R6 verbatim]
        if (do_pe) {
            const int g0 = SS - 1 + j0 - i0 - 63;          // in [0, 960]
#pragma unroll
            for (int u = 0; u < 4; u++) {
                int c = tid + 256 * u;
                int o = c >> 3, k8 = c & 7;
                int g = g0 + o;
                half8 v = {0, 0, 0, 0, 0, 0, 0, 0};
                if (g < SS) v = *(const half8*)(peh + (size_t)g * DHH + k8 * 8);
                *(half8*)(PEb + o * 72 + k8 * 8) = v;
            }
        }
        float mj_f[4];
#pragma unroll
        for (int nb = 0; nb < 4; nb++)
            mj_f[nb] = (float)mask[b * SS + j0 + nb * 16 + lm];
        __syncthreads();                                   // (b) staging visible

        // ---- QK^T  [R6 verbatim]
        v4f sacc[4];
#pragma unroll
        for (int nb = 0; nb < 4; nb++) sacc[nb] = zero4;
#pragma unroll
        for (int nb = 0; nb < 4; nb++)
#pragma unroll
            for (int kc = 0; kc < 2; kc++) {
                half8 kf = *(const half8*)(Ks + (nb * 16 + lm) * 72 + kc * 32 + quad * 8);
                sacc[nb] = __builtin_amdgcn_mfma_f32_16x16x32_f16(qf[kc], kf, sacc[nb], 0, 0, 0);
            }

        // ---- relative position band: 5 tiles + shfl gather  [BISECT VAR A]
        if (do_pe) {
            v4f racc[5];
#pragma unroll
            for (int e = 0; e < 5; e++) racc[e] = zero4;
#pragma unroll
            for (int e = 0; e < 5; e++) {
                int row = (e + 3 - w) * 16 + lm;
#pragma unroll
                for (int kc = 0; kc < 2; kc++) {
                    half8 pf = *(const half8*)(PEb + row * 72 + kc * 32 + quad * 8);
                    racc[e] = __builtin_amdgcn_mfma_f32_16x16x32_f16(qf[kc], pf, racc[e], 0, 0, 0);
                }
            }
#pragma unroll
            for (int nb = 0; nb < 4; nb++)
#pragma unroll
                for (int r = 0; r < 4; r++) {
                    int qr = quad * 4 + r;
                    float vsrc = (((lm + qr + 1) & 15) <= qr)
                               ? racc[nb][r] : racc[nb + 1][r];
                    int src = (lane & 48) | ((lm - qr - 1) & 15);
                    sacc[nb][r] += __shfl(vsrc, src);
                }
        }

        // ---- mask + online softmax  [R6 verbatim]
        float p[4][4];
        float alpha[4];
#pragma unroll
        for (int i = 0; i < 4; i++) {
            float mi = mi_f[i];
            float rmax = -1e30f;
#pragma unroll
            for (int j = 0; j < 4; j++) {
                float s = sacc[j][i];
                if (mi * mj_f[j] == 0.f) s = -1e9f;
                sacc[j][i] = s;
                rmax = fmaxf(rmax, s);
            }
#pragma unroll
            for (int off = 1; off < 16; off <<= 1)
                rmax = fmaxf(rmax, __shfl_xor(rmax, off));
            float mnew = fmaxf(m_run[i], rmax);
            alpha[i] = __expf(m_run[i] - mnew);
            m_run[i] = mnew;
            float rsum = 0.f;
#pragma unroll
            for (int j = 0; j < 4; j++) {
                p[j][i] = __expf(sacc[j][i] - mnew);
                rsum += p[j][i];
            }
#pragma unroll
            for (int off = 1; off < 16; off <<= 1)
                rsum += __shfl_xor(rsum, off);
            l_run[i] = l_run[i] * alpha[i] + rsum;
        }

        // write P (f16) into dedicated per-wave buffer; rescale O
        _Float16* Pw = &Pb[w][0];
#pragma unroll
        for (int nb = 0; nb < 4; nb++)
#pragma unroll
            for (int r = 0; r < 4; r++)
                Pw[(quad * 4 + r) * 72 + nb * 16 + lm] = (_Float16)p[nb][r];
#pragma unroll
        for (int nb = 0; nb < 4; nb++)
#pragma unroll
            for (int r = 0; r < 4; r++) oacc[nb][r] *= alpha[r];
        __syncthreads();                                   // (e) P visible

        // ---- PV  [R6 verbatim]
#pragma unroll
        for (int kc = 0; kc < 2; kc++) {
            half8 pfrag = *(const half8*)(Pw + lm * 72 + kc * 32 + quad * 8);
#pragma unroll
            for (int nb = 0; nb < 4; nb++) {
                half8 vfrag = *(const half8*)(Vt + (nb * 16 + lm) * 72 + kc * 32 + quad * 8);
                oacc[nb] = __builtin_amdgcn_mfma_f32_16x16x32_f16(pfrag, vfrag, oacc[nb], 0, 0, 0);
            }
        }
    }

    // epilogue: normalize, write f16 [B,S,D]
#pragma unroll
    for (int r = 0; r < 4; r++) {
        float inv = 1.f / l_run[r];
        int s = i0 + w * 16 + quad * 4 + r;
#pragma unroll
        for (int nb = 0; nb < 4; nb++)
            Og[((size_t)b * SS + s) * DD + h * DHH + nb * 16 + lm] =
                (_Float16)(oacc[nb][r] * inv);
    }
}

extern "C" void kernel_launch(void* const* d_in, const int* in_sizes, int n_in,
                              void* d_out, int out_size, void* d_ws, size_t ws_size,
                              hipStream_t stream)
{
    const float* query = (const float*)d_in[0];
    const float* key   = (const float*)d_in[1];
    const float* value = (const float*)d_in[2];
    const int*   mask  = (const int*)d_in[3];
    const float* pe    = (const float*)d_in[4];
    const float* Wq    = (const float*)d_in[5];
    const float* Wk    = (const float*)d_in[6];
    const float* Wv    = (const float*)d_in[7];
    const float* Wo    = (const float*)d_in[8];
    float* out = (float*)d_out;

    _Float16* ws16 = (_Float16*)d_ws;
    const size_t MEG = 1048576;
    _Float16* wqf = ws16;
    _Float16* wkf = ws16 + 1 * MEG;
    _Float16* wvf = ws16 + 2 * MEG;
    _Float16* wof = ws16 + 3 * MEG;
    _Float16* pef = ws16 + 4 * MEG;
    _Float16* qp  = ws16 + 5 * MEG;     // [B,H,S,DH]
    _Float16* kp  = ws16 + 9 * MEG;     // [B,H,S,DH]
    _Float16* vp  = ws16 + 13 * MEG;    // [B,H,S,DH]
    _Float16* ao  = ws16 + 17 * MEG;    // [B,S,D]

    convert_kernel<<<5120, 256, 0, stream>>>(Wq, Wk, Wv, Wo, pe, ws16);

    gemm_proj<<<dim3(DD / 64, (BB * SS) / 128, 3), 256, 0, stream>>>(
        query, key, value, wqf, wkf, wvf, qp, kp, vp);

    attn_mfma<<<dim3(SS / 64, BB * HH), 256, 0, stream>>>(qp, kp, vp, mask, pef, ao);

    gemm_out<<<dim3(DD / 64, (BB * SS) / 128), 256, 0, stream>>>(ao, wof, out);
}